// Round 1
// baseline (237.905 us; speedup 1.0000x reference)
//
#include <hip/hip_runtime.h>

typedef unsigned short u16;
typedef __attribute__((ext_vector_type(8))) short short8;    // 8 bf16 (4 VGPRs)
typedef __attribute__((ext_vector_type(4))) float f32x4;
typedef __attribute__((ext_vector_type(16))) float f32x16;
typedef __attribute__((ext_vector_type(4))) unsigned short u16x4;
typedef __attribute__((ext_vector_type(2))) unsigned int uint2v;

typedef __attribute__((address_space(1))) void as1_void;
typedef __attribute__((address_space(3))) void as3_void;

// async global->LDS, 16B per lane; LDS dest = wave-uniform base + lane*16
__device__ __forceinline__ void gld16(const u16* g, u16* l) {
  __builtin_amdgcn_global_load_lds((as1_void*)g, (as3_void*)l, 16, 0, 0);
}

__device__ __forceinline__ u16 f2bf(float f) {
  unsigned u = __float_as_uint(f);
  u += 0x7fffu + ((u >> 16) & 1u);   // RNE
  return (u16)(u >> 16);
}

__device__ __forceinline__ short8 mk8(unsigned a, unsigned b, unsigned c, unsigned d) {
  union { unsigned u[4]; short8 s; } x;
  x.u[0] = a; x.u[1] = b; x.u[2] = c; x.u[3] = d;
  return x.s;
}

// ---------------- fused prep: cvt x (x4) + W_eff + cvt wo ----------------
// blocks [0,3072): x cvt vectorized; [3072,12288): weff rows 0..2303, wob rows 2304..3071
__global__ void prep_all(const float* __restrict__ x, u16* __restrict__ xb,
                         const float* __restrict__ wq, const float* __restrict__ wk, const float* __restrict__ wv,
                         const float* __restrict__ dq, const float* __restrict__ uq,
                         const float* __restrict__ dk, const float* __restrict__ uk,
                         const float* __restrict__ dv, const float* __restrict__ uv,
                         const float* __restrict__ wo, u16* __restrict__ weff, u16* __restrict__ wob) {
  int bid = blockIdx.x;
  if (bid < 3072) {
    int i = bid * 256 + threadIdx.x;          // < 786432
    f32x4 f = *(const f32x4*)(x + (size_t)i * 4);
    u16x4 o;
#pragma unroll
    for (int r = 0; r < 4; ++r) o[r] = f2bf(f[r]);
    *(u16x4*)(xb + (size_t)i * 4) = o;
    return;
  }
  int idx = (bid - 3072) * 256 + threadIdx.x; // < 3072*768
  int n = idx / 768, d = idx - n * 768;
  if (n >= 2304) {
    wob[(n - 2304) * 768 + d] = f2bf(wo[(n - 2304) * 768 + d]);
    return;
  }
  const float *w, *dn, *up; int e;
  if (n < 768)       { w = wq; dn = dq; up = uq; e = n; }
  else if (n < 1536) { w = wk; dn = dk; up = uk; e = n - 768; }
  else               { w = wv; dn = dv; up = uv; e = n - 1536; }
  float acc = w[e * 768 + d];
  float lo = 0.f;
#pragma unroll
  for (int r = 0; r < 8; ++r) lo += up[e * 8 + r] * dn[r * 768 + d];
  weff[idx] = f2bf(acc + 2.0f * lo);   // SCALING = alpha/rank = 2
}

// ---------------- NT GEMM: C[m,n] = sum_k A[m,k]*B[n,k] (+bias) ----------------
// MT x 128 block tile, BK=32, 256 thr. MT=128: 2x2 waves of 64x64. MT=32: 1x4 waves of 32x32.
// mode 0: N=2304 -> q[h][s][64] (pre-scaled by 0.125*log2e), k[h][s][64], vt[h][64][s]
// mode 1: N=768  -> fo[s][768] fp32 (+bo)
template <int MT>
__global__ __launch_bounds__(256) void gemm_nt(
    const u16* __restrict__ A, const u16* __restrict__ B, int K, int mode,
    const float* __restrict__ bq, const float* __restrict__ bk, const float* __restrict__ bv,
    u16* __restrict__ qo, u16* __restrict__ ko, u16* __restrict__ vto,
    const float* __restrict__ bo, float* __restrict__ fo) {
  constexpr int TI = (MT == 128) ? 4 : 2;
  constexpr int TJ = (MT == 128) ? 4 : 2;
  __shared__ u16 As[MT * 32];
  __shared__ u16 Bs[128 * 32];
  const int tid = threadIdx.x;
  const int lane = tid & 63;
  const int wid = tid >> 6;
  const int qd = lane >> 4;
  const int m16 = lane & 15;
  const int rowbase = (MT == 128) ? (wid >> 1) * 64 : 0;
  const int colbase = (MT == 128) ? (wid & 1) * 64 : wid * 32;
  const int m0 = blockIdx.x * MT, n0 = blockIdx.y * 128;

  f32x4 acc[TI][TJ];
#pragma unroll
  for (int i = 0; i < TI; ++i)
#pragma unroll
    for (int j = 0; j < TJ; ++j)
#pragma unroll
      for (int e = 0; e < 4; ++e) acc[i][j][e] = 0.f;

  for (int k0 = 0; k0 < K; k0 += 32) {
    __syncthreads();
#pragma unroll
    for (int p = tid; p < MT * 4; p += 256) {
      int row = p >> 2;
      int g = (p & 3) ^ ((row >> 1) & 3);
      gld16(A + (size_t)(m0 + row) * K + k0 + g * 8, &As[(p - lane) * 8]);
    }
#pragma unroll
    for (int p = tid; p < 512; p += 256) {
      int row = p >> 2;
      int g = (p & 3) ^ ((row >> 1) & 3);
      gld16(B + (size_t)(n0 + row) * K + k0 + g * 8, &Bs[(p - lane) * 8]);
    }
    __syncthreads();
    short8 af[TI], bf[TJ];
#pragma unroll
    for (int i = 0; i < TI; ++i) {
      int ar = rowbase + i * 16 + m16;
      af[i] = *(const short8*)&As[(ar * 4 + (qd ^ ((ar >> 1) & 3))) * 8];
    }
#pragma unroll
    for (int j = 0; j < TJ; ++j) {
      int br = colbase + j * 16 + m16;
      bf[j] = *(const short8*)&Bs[(br * 4 + (qd ^ ((br >> 1) & 3))) * 8];
    }
#pragma unroll
    for (int i = 0; i < TI; ++i)
#pragma unroll
      for (int j = 0; j < TJ; ++j)
        acc[i][j] = __builtin_amdgcn_mfma_f32_16x16x32_bf16(af[i], bf[j], acc[i][j], 0, 0, 0);
  }

  // C/D layout: col = m16, row = qd*4 + reg
#pragma unroll
  for (int i = 0; i < TI; ++i) {
    int gr = m0 + rowbase + i * 16 + qd * 4;
#pragma unroll
    for (int j = 0; j < TJ; ++j) {
      int gc = n0 + colbase + j * 16 + m16;
      if (mode == 0) {
        if (gc < 768) {
          float bias = bq[gc];
          int h = gc >> 6, d = gc & 63;
          // fold attention scale 1/8 and log2(e) into Q: exp(x/8) = exp2(x*0.18034)
#pragma unroll
          for (int r = 0; r < 4; ++r)
            qo[((size_t)h * 4096 + gr + r) * 64 + d] = f2bf((acc[i][j][r] + bias) * 0.18033688f);
        } else if (gc < 1536) {
          int c = gc - 768;
          float bias = bk[c];
          int h = c >> 6, d = c & 63;
#pragma unroll
          for (int r = 0; r < 4; ++r)
            ko[((size_t)h * 4096 + gr + r) * 64 + d] = f2bf(acc[i][j][r] + bias);
        } else {
          int c = gc - 1536;
          float bias = bv[c];
          int h = c >> 6, d = c & 63;
          u16x4 pk;
#pragma unroll
          for (int r = 0; r < 4; ++r) pk[r] = f2bf(acc[i][j][r] + bias);
          *(u16x4*)&vto[((size_t)h * 64 + d) * 4096 + gr] = pk;
        }
      } else {
        float bias = bo[gc];
#pragma unroll
        for (int r = 0; r < 4; ++r)
          fo[(size_t)(gr + r) * 768 + gc] = acc[i][j][r] + bias;
      }
    }
  }
}

// ---------------- flash attention fwd (S^T form, fixed-max base-2 softmax) ----------------
// grid (16 qblocks, 12 heads, kspl), 256 thr / 4 waves. Wave owns 64 q-rows = 2 q-tiles of 32.
// 32x32x16 MFMA throughout (half the MFMA instruction count of the 16x16x32 version).
// Swapped QK^T: S^T = K*Q^T, so lane (q32=lane&31, hf=lane>>5) holds 16 scores of q-row q32,
// k = (reg&3)+8*(reg>>2)+4*hf. Softmax fully in-register; P transposed for PV via
// v_cvt_pk_bf16_f32 (2 f32 -> word) + permlane32_swap pairing (w0,w2)/(w1,w3):
//   swap(a,b) -> {.x = [a_lo | b_lo^], .y = [a_hi_v | b_hi]}  (dst-upper <-> src-lower)
// which yields exactly the A-fragment layout k = (lane>>5)*8 + j. NO P LDS round-trip.
// K buf 64x64 (8 chunks/row, phys = row*8 + (c ^ (row&7))); V^T buf 64d x 64k same swizzle,
// DOUBLE-BUFFERED with ONE barrier per iter (issue gld16 for it+1 right after barrier).
// LDS = 2*8K (Ks) + 2*8K (Vs) = 32 KB (P buffer deleted).
__global__ __launch_bounds__(256) void attn_fwd(
    const u16* __restrict__ Q, const u16* __restrict__ Kg, const u16* __restrict__ Vt,
    float* __restrict__ Opart, float* __restrict__ lpart, u16* __restrict__ abo, int kspl) {
  __shared__ u16 Ks[2][64 * 64];
  __shared__ u16 Vs[2][64 * 64];
  const int tid = threadIdx.x, lane = tid & 63, wid = tid >> 6;
  const int q32 = lane & 31, hf = lane >> 5;
  const int h = blockIdx.y;
  const int qrow = blockIdx.x * 256 + wid * 64;
  const int kbase = blockIdx.z * (4096 / kspl);
  const int niter = (4096 / kspl) >> 6;

  // Q fragments (B-operand of K*Q^T): qf[t][ds] = Q[qrow+32t+q32][ds*16 + hf*8 ..+8)
  short8 qf[2][4];
#pragma unroll
  for (int t = 0; t < 2; ++t) {
    const u16* qb = Q + ((size_t)h * 4096 + qrow + 32 * t + q32) * 64 + hf * 8;
#pragma unroll
    for (int ds = 0; ds < 4; ++ds) qf[t][ds] = *(const short8*)(qb + ds * 16);
  }

  float lrun[2] = {0.f, 0.f};
  f32x16 oacc[2][2];
#pragma unroll
  for (int t = 0; t < 2; ++t)
#pragma unroll
    for (int d = 0; d < 2; ++d)
#pragma unroll
      for (int r = 0; r < 16; ++r) oacc[t][d][r] = 0.f;

  const u16* kgh = Kg + (size_t)h * 4096 * 64;
  const u16* vth = Vt + (size_t)h * 64 * 4096;

  // prologue: stage iter 0 into buffer 0
  {
    const int kt = kbase;
#pragma unroll
    for (int rr = 0; rr < 2; ++rr) {
      int p = rr * 256 + tid;                 // 0..511 chunks
      int row = p >> 3;
      int g = (p & 7) ^ (row & 7);
      gld16(kgh + (size_t)(kt + row) * 64 + g * 8, &Ks[0][(p - lane) * 8]);
      gld16(vth + (size_t)row * 4096 + kt + g * 8, &Vs[0][(p - lane) * 8]);
    }
  }

  for (int it = 0; it < niter; ++it) {
    __syncthreads();   // buf[it&1] staged (issued last iter); prev reads of buf^1 done
    if (it + 1 < niter) {
      const int kt = kbase + (it + 1) * 64;
      const int b = (it + 1) & 1;
#pragma unroll
      for (int rr = 0; rr < 2; ++rr) {
        int p = rr * 256 + tid;
        int row = p >> 3;
        int g = (p & 7) ^ (row & 7);
        gld16(kgh + (size_t)(kt + row) * 64 + g * 8, &Ks[b][(p - lane) * 8]);
        gld16(vth + (size_t)row * 4096 + kt + g * 8, &Vs[b][(p - lane) * 8]);
      }
    }
    const u16* ks = Ks[it & 1];
    const u16* vs = Vs[it & 1];

#pragma unroll
    for (int kst = 0; kst < 2; ++kst) {       // 32-k subtile
      const int krow = kst * 32 + q32;
      short8 kf[4];
#pragma unroll
      for (int ds = 0; ds < 4; ++ds) {
        int c = ds * 2 + hf;
        kf[ds] = *(const short8*)&ks[((krow << 3) + (c ^ (krow & 7))) * 8];
      }
      short8 pa[2][2];
#pragma unroll
      for (int t = 0; t < 2; ++t) {
        f32x16 s;
#pragma unroll
        for (int r = 0; r < 16; ++r) s[r] = 0.f;
#pragma unroll
        for (int ds = 0; ds < 4; ++ds)
          s = __builtin_amdgcn_mfma_f32_32x32x16_bf16(kf[ds], qf[t][ds], s, 0, 0, 0);
        unsigned w[8];
        float ls = 0.f;
#pragma unroll
        for (int i = 0; i < 8; ++i) {
          float p0 = __builtin_amdgcn_exp2f(s[2 * i]);
          float p1 = __builtin_amdgcn_exp2f(s[2 * i + 1]);
          ls += p0 + p1;
          asm("v_cvt_pk_bf16_f32 %0, %1, %2" : "=v"(w[i]) : "v"(p0), "v"(p1));
        }
        lrun[t] += ls;
        uint2v r0 = __builtin_amdgcn_permlane32_swap(w[0], w[2], false, false);
        uint2v r1 = __builtin_amdgcn_permlane32_swap(w[1], w[3], false, false);
        uint2v r2 = __builtin_amdgcn_permlane32_swap(w[4], w[6], false, false);
        uint2v r3 = __builtin_amdgcn_permlane32_swap(w[5], w[7], false, false);
        pa[t][0] = mk8(r0[0], r1[0], r0[1], r1[1]);   // k-slice kst*32 + [0,16)
        pa[t][1] = mk8(r2[0], r3[0], r2[1], r3[1]);   // k-slice kst*32 + [16,32)
      }
      // O += P V for this subtile (all in registers; V from swizzled LDS)
#pragma unroll
      for (int dt = 0; dt < 2; ++dt) {
        const int vrow = dt * 32 + q32;
#pragma unroll
        for (int ksl = 0; ksl < 2; ++ksl) {
          int c = kst * 4 + ksl * 2 + hf;
          short8 vf = *(const short8*)&vs[((vrow << 3) + (c ^ (vrow & 7))) * 8];
#pragma unroll
          for (int t = 0; t < 2; ++t)
            oacc[t][dt] = __builtin_amdgcn_mfma_f32_32x32x16_bf16(pa[t][ksl], vf, oacc[t][dt], 0, 0, 0);
        }
      }
    }
  }

  // each half holds a disjoint k-partial of the row sum; combine across halves
#pragma unroll
  for (int t = 0; t < 2; ++t) lrun[t] += __shfl_xor(lrun[t], 32);

  if (kspl > 1) {
#pragma unroll
    for (int t = 0; t < 2; ++t)
      if (hf == 0)
        lpart[((size_t)blockIdx.z * 4096 + qrow + 32 * t + q32) * 12 + h] = lrun[t];
    float* ob = Opart + (size_t)blockIdx.z * 4096 * 768;
#pragma unroll
    for (int t = 0; t < 2; ++t)
#pragma unroll
      for (int r = 0; r < 16; ++r) {
        int qloc = (r & 3) + 8 * (r >> 2) + 4 * hf;
#pragma unroll
        for (int dt = 0; dt < 2; ++dt)
          ob[(size_t)(qrow + 32 * t + qloc) * 768 + h * 64 + dt * 32 + q32] = oacc[t][dt][r];
      }
  } else {
#pragma unroll
    for (int t = 0; t < 2; ++t) {
      float linv = 1.0f / lrun[t];
#pragma unroll
      for (int r = 0; r < 16; ++r) {
        int qloc = (r & 3) + 8 * (r >> 2) + 4 * hf;
        float li = __shfl(linv, qloc);
#pragma unroll
        for (int dt = 0; dt < 2; ++dt)
          abo[(size_t)(qrow + 32 * t + qloc) * 768 + h * 64 + dt * 32 + q32] =
              f2bf(oacc[t][dt][r] * li);
      }
    }
  }
}

// ---------------- merge ksp k-split partials + normalize -> bf16, x4 ----------------
__global__ void merge_norm(const float* __restrict__ Opart, const float* __restrict__ lpart,
                           u16* __restrict__ abo, int ksp) {
  int i = blockIdx.x * 256 + threadIdx.x;   // < 786432 (4096*768/4)
  int s = i / 192, cq = i - s * 192;
  int h = cq >> 4;                          // (cq*4)>>6
  f32x4 a = {0.f, 0.f, 0.f, 0.f};
  float l = 0.f;
  for (int z = 0; z < ksp; ++z) {
    f32x4 b = *(const f32x4*)(Opart + (size_t)z * 4096 * 768 + (size_t)i * 4);
#pragma unroll
    for (int r = 0; r < 4; ++r) a[r] += b[r];
    l += lpart[((size_t)z * 4096 + s) * 12 + h];
  }
  float rl = 1.0f / l;
  u16x4 o;
#pragma unroll
  for (int r = 0; r < 4; ++r) o[r] = f2bf(a[r] * rl);
  *(u16x4*)(abo + (size_t)i * 4) = o;
}

extern "C" void kernel_launch(void* const* d_in, const int* in_sizes, int n_in,
                              void* d_out, int out_size, void* d_ws, size_t ws_size,
                              hipStream_t stream) {
  const float* x   = (const float*)d_in[0];
  const float* wq  = (const float*)d_in[1];
  const float* bq  = (const float*)d_in[2];
  const float* wk  = (const float*)d_in[3];
  const float* bk  = (const float*)d_in[4];
  const float* wv  = (const float*)d_in[5];
  const float* bv  = (const float*)d_in[6];
  const float* wo  = (const float*)d_in[7];
  const float* bo  = (const float*)d_in[8];
  const float* dq  = (const float*)d_in[9];
  const float* uq  = (const float*)d_in[10];
  const float* dk  = (const float*)d_in[11];
  const float* uk  = (const float*)d_in[12];
  const float* dv  = (const float*)d_in[13];
  const float* uv  = (const float*)d_in[14];
  float* out = (float*)d_out;

  char* ws = (char*)d_ws;
  u16* xb    = (u16*)(ws);                 // 4096*768 bf16 (6291456 B); dead after QKV gemm
  u16* ab    = (u16*)(ws);                 // aliases xb: attn output [4096][768] bf16
  u16* weff  = (u16*)(ws + 6291456);       // 2304*768
  u16* wob   = (u16*)(ws + 9830400);       // 768*768
  u16* qb    = (u16*)(ws + 11010048);      // [12][4096][64]
  u16* kb    = (u16*)(ws + 17301504);      // [12][4096][64]
  u16* vtb   = (u16*)(ws + 23592960);      // [12][64][4096]
  float* Op  = (float*)(ws + 29884416);    // [kspl][4096][768] f32 (<= 50331648 B)
  float* lp  = (float*)(ws + 80216064);    // [kspl][4096][12]  f32 (<= 786432 B) -> end 81002496

  int kspl = 1;
  if (ws_size >= 81002496ull) kspl = 4;
  else if (ws_size >= 55443456ull) {
    kspl = 2;
    lp = (float*)(ws + 55050240);          // pack tighter for the 2-split case
  }

  prep_all<<<12288, 256, 0, stream>>>(x, xb, wq, wk, wv, dq, uq, dk, uk, dv, uv, wo, weff, wob);
  gemm_nt<128><<<dim3(32, 18), 256, 0, stream>>>(xb, weff, 768, 0, bq, bk, bv, qb, kb, vtb,
                                                 nullptr, nullptr);
  attn_fwd<<<dim3(16, 12, kspl), 256, 0, stream>>>(qb, kb, vtb, Op, lp, ab, kspl);
  if (kspl > 1) merge_norm<<<3072, 256, 0, stream>>>(Op, lp, ab, kspl);
  gemm_nt<32><<<dim3(128, 6), 256, 0, stream>>>(ab, wob, 768, 1, nullptr, nullptr, nullptr,
                                                nullptr, nullptr, nullptr, bo, out);
}

// Round 2
// 217.611 us; speedup vs baseline: 1.0933x; 1.0933x over previous
//
#include <hip/hip_runtime.h>

typedef unsigned short u16;
typedef __attribute__((ext_vector_type(8))) short short8;    // 8 bf16 (4 VGPRs)
typedef __attribute__((ext_vector_type(4))) float f32x4;
typedef __attribute__((ext_vector_type(16))) float f32x16;
typedef __attribute__((ext_vector_type(4))) unsigned short u16x4;
typedef __attribute__((ext_vector_type(2))) unsigned int uint2v;

typedef __attribute__((address_space(1))) void as1_void;
typedef __attribute__((address_space(3))) void as3_void;

// async global->LDS, 16B per lane; LDS dest = wave-uniform base + lane*16
__device__ __forceinline__ void gld16(const u16* g, u16* l) {
  __builtin_amdgcn_global_load_lds((as1_void*)g, (as3_void*)l, 16, 0, 0);
}

__device__ __forceinline__ u16 f2bf(float f) {
  unsigned u = __float_as_uint(f);
  u += 0x7fffu + ((u >> 16) & 1u);   // RNE
  return (u16)(u >> 16);
}

__device__ __forceinline__ short8 mk8(unsigned a, unsigned b, unsigned c, unsigned d) {
  union { unsigned u[4]; short8 s; } x;
  x.u[0] = a; x.u[1] = b; x.u[2] = c; x.u[3] = d;
  return x.s;
}

// ---------------- fused prep: cvt x (x4) + W_eff + cvt wo ----------------
// blocks [0,3072): x cvt vectorized; [3072,12288): weff rows 0..2303, wob rows 2304..3071
__global__ void prep_all(const float* __restrict__ x, u16* __restrict__ xb,
                         const float* __restrict__ wq, const float* __restrict__ wk, const float* __restrict__ wv,
                         const float* __restrict__ dq, const float* __restrict__ uq,
                         const float* __restrict__ dk, const float* __restrict__ uk,
                         const float* __restrict__ dv, const float* __restrict__ uv,
                         const float* __restrict__ wo, u16* __restrict__ weff, u16* __restrict__ wob) {
  int bid = blockIdx.x;
  if (bid < 3072) {
    int i = bid * 256 + threadIdx.x;          // < 786432
    f32x4 f = *(const f32x4*)(x + (size_t)i * 4);
    u16x4 o;
#pragma unroll
    for (int r = 0; r < 4; ++r) o[r] = f2bf(f[r]);
    *(u16x4*)(xb + (size_t)i * 4) = o;
    return;
  }
  int idx = (bid - 3072) * 256 + threadIdx.x; // < 3072*768
  int n = idx / 768, d = idx - n * 768;
  if (n >= 2304) {
    wob[(n - 2304) * 768 + d] = f2bf(wo[(n - 2304) * 768 + d]);
    return;
  }
  const float *w, *dn, *up; int e;
  if (n < 768)       { w = wq; dn = dq; up = uq; e = n; }
  else if (n < 1536) { w = wk; dn = dk; up = uk; e = n - 768; }
  else               { w = wv; dn = dv; up = uv; e = n - 1536; }
  float acc = w[e * 768 + d];
  float lo = 0.f;
#pragma unroll
  for (int r = 0; r < 8; ++r) lo += up[e * 8 + r] * dn[r * 768 + d];
  weff[idx] = f2bf(acc + 2.0f * lo);   // SCALING = alpha/rank = 2
}

// ---------------- NT GEMM: C[m,n] = sum_k A[m,k]*B[n,k] (+bias) ----------------
// MT x 128 block tile, BK=32, 256 thr. MT=128: 2x2 waves of 64x64. MT=32: 1x4 waves of 32x32.
// mode 0: N=2304 -> q[h][s][64] (pre-scaled by 0.125*log2e), k[h][s][64], vt[h][64][s]
// mode 1: N=768  -> fo[s][768] fp32 (+bo)
template <int MT>
__global__ __launch_bounds__(256) void gemm_nt(
    const u16* __restrict__ A, const u16* __restrict__ B, int K, int mode,
    const float* __restrict__ bq, const float* __restrict__ bk, const float* __restrict__ bv,
    u16* __restrict__ qo, u16* __restrict__ ko, u16* __restrict__ vto,
    const float* __restrict__ bo, float* __restrict__ fo) {
  constexpr int TI = (MT == 128) ? 4 : 2;
  constexpr int TJ = (MT == 128) ? 4 : 2;
  __shared__ u16 As[MT * 32];
  __shared__ u16 Bs[128 * 32];
  const int tid = threadIdx.x;
  const int lane = tid & 63;
  const int wid = tid >> 6;
  const int qd = lane >> 4;
  const int m16 = lane & 15;
  const int rowbase = (MT == 128) ? (wid >> 1) * 64 : 0;
  const int colbase = (MT == 128) ? (wid & 1) * 64 : wid * 32;
  const int m0 = blockIdx.x * MT, n0 = blockIdx.y * 128;

  f32x4 acc[TI][TJ];
#pragma unroll
  for (int i = 0; i < TI; ++i)
#pragma unroll
    for (int j = 0; j < TJ; ++j)
#pragma unroll
      for (int e = 0; e < 4; ++e) acc[i][j][e] = 0.f;

  for (int k0 = 0; k0 < K; k0 += 32) {
    __syncthreads();
#pragma unroll
    for (int p = tid; p < MT * 4; p += 256) {
      int row = p >> 2;
      int g = (p & 3) ^ ((row >> 1) & 3);
      gld16(A + (size_t)(m0 + row) * K + k0 + g * 8, &As[(p - lane) * 8]);
    }
#pragma unroll
    for (int p = tid; p < 512; p += 256) {
      int row = p >> 2;
      int g = (p & 3) ^ ((row >> 1) & 3);
      gld16(B + (size_t)(n0 + row) * K + k0 + g * 8, &Bs[(p - lane) * 8]);
    }
    __syncthreads();
    short8 af[TI], bf[TJ];
#pragma unroll
    for (int i = 0; i < TI; ++i) {
      int ar = rowbase + i * 16 + m16;
      af[i] = *(const short8*)&As[(ar * 4 + (qd ^ ((ar >> 1) & 3))) * 8];
    }
#pragma unroll
    for (int j = 0; j < TJ; ++j) {
      int br = colbase + j * 16 + m16;
      bf[j] = *(const short8*)&Bs[(br * 4 + (qd ^ ((br >> 1) & 3))) * 8];
    }
#pragma unroll
    for (int i = 0; i < TI; ++i)
#pragma unroll
      for (int j = 0; j < TJ; ++j)
        acc[i][j] = __builtin_amdgcn_mfma_f32_16x16x32_bf16(af[i], bf[j], acc[i][j], 0, 0, 0);
  }

  // C/D layout: col = m16, row = qd*4 + reg
#pragma unroll
  for (int i = 0; i < TI; ++i) {
    int gr = m0 + rowbase + i * 16 + qd * 4;
#pragma unroll
    for (int j = 0; j < TJ; ++j) {
      int gc = n0 + colbase + j * 16 + m16;
      if (mode == 0) {
        if (gc < 768) {
          float bias = bq[gc];
          int h = gc >> 6, d = gc & 63;
          // fold attention scale 1/8 and log2(e) into Q: exp(x/8) = exp2(x*0.18034)
#pragma unroll
          for (int r = 0; r < 4; ++r)
            qo[((size_t)h * 4096 + gr + r) * 64 + d] = f2bf((acc[i][j][r] + bias) * 0.18033688f);
        } else if (gc < 1536) {
          int c = gc - 768;
          float bias = bk[c];
          int h = c >> 6, d = c & 63;
#pragma unroll
          for (int r = 0; r < 4; ++r)
            ko[((size_t)h * 4096 + gr + r) * 64 + d] = f2bf(acc[i][j][r] + bias);
        } else {
          int c = gc - 1536;
          float bias = bv[c];
          int h = c >> 6, d = c & 63;
          u16x4 pk;
#pragma unroll
          for (int r = 0; r < 4; ++r) pk[r] = f2bf(acc[i][j][r] + bias);
          *(u16x4*)&vto[((size_t)h * 64 + d) * 4096 + gr] = pk;
        }
      } else {
        float bias = bo[gc];
#pragma unroll
        for (int r = 0; r < 4; ++r)
          fo[(size_t)(gr + r) * 768 + gc] = acc[i][j][r] + bias;
      }
    }
  }
}

// ---------------- flash attention fwd (S^T form, fixed-max base-2 softmax) ----------------
// grid (32 qblocks, 12 heads, kspl), 256 thr / 4 waves. Wave owns ONE 32-q-row tile.
// (Round-1 lesson: 64 q-rows/wave -> only 1.5 waves/SIMD; latency chain fully exposed,
//  MfmaUtil 21% with all pipes idle. Halving the wave tile doubles wave-tasks to 1536*kspl
//  and at kspl=2 gives 768 blocks = exactly 3/CU, 3 waves/SIMD, VGPR back under 128.)
// 32x32x16 MFMA. Swapped QK^T: S^T = K*Q^T, lane (q32=lane&31, hf=lane>>5) holds 16 scores
// of q-row q32, k = (reg&3)+8*(reg>>2)+4*hf. Softmax in-register; P for PV built via
// v_cvt_pk_bf16_f32 + permlane32_swap pairing (w0,w2)/(w1,w3) -> A-frag layout k=(l>>5)*8+j.
// K buf 64x64 (8 chunks/row, phys = row*8 + (c ^ (row&7))); V^T buf 64d x 64k same swizzle,
// DOUBLE-BUFFERED with ONE barrier per iter (issue gld16 for it+1 right after barrier).
// LDS = 2*8K (Ks) + 2*8K (Vs) = 32 KB.
__global__ __launch_bounds__(256) void attn_fwd(
    const u16* __restrict__ Q, const u16* __restrict__ Kg, const u16* __restrict__ Vt,
    float* __restrict__ Opart, float* __restrict__ lpart, u16* __restrict__ abo, int kspl) {
  __shared__ u16 Ks[2][64 * 64];
  __shared__ u16 Vs[2][64 * 64];
  const int tid = threadIdx.x, lane = tid & 63, wid = tid >> 6;
  const int q32 = lane & 31, hf = lane >> 5;
  const int h = blockIdx.y;
  const int qrow = blockIdx.x * 128 + wid * 32;
  const int kbase = blockIdx.z * (4096 / kspl);
  const int niter = (4096 / kspl) >> 6;

  // Q fragment (B-operand of K*Q^T): qf[ds] = Q[qrow+q32][ds*16 + hf*8 ..+8)
  short8 qf[4];
  {
    const u16* qb = Q + ((size_t)h * 4096 + qrow + q32) * 64 + hf * 8;
#pragma unroll
    for (int ds = 0; ds < 4; ++ds) qf[ds] = *(const short8*)(qb + ds * 16);
  }

  float lrun = 0.f;
  f32x16 oacc[2];
#pragma unroll
  for (int d = 0; d < 2; ++d)
#pragma unroll
    for (int r = 0; r < 16; ++r) oacc[d][r] = 0.f;

  const u16* kgh = Kg + (size_t)h * 4096 * 64;
  const u16* vth = Vt + (size_t)h * 64 * 4096;

  // prologue: stage iter 0 into buffer 0
  {
    const int kt = kbase;
#pragma unroll
    for (int rr = 0; rr < 2; ++rr) {
      int p = rr * 256 + tid;                 // 0..511 chunks
      int row = p >> 3;
      int g = (p & 7) ^ (row & 7);
      gld16(kgh + (size_t)(kt + row) * 64 + g * 8, &Ks[0][(p - lane) * 8]);
      gld16(vth + (size_t)row * 4096 + kt + g * 8, &Vs[0][(p - lane) * 8]);
    }
  }

  for (int it = 0; it < niter; ++it) {
    __syncthreads();   // buf[it&1] staged (issued last iter); prev reads of buf^1 done
    if (it + 1 < niter) {
      const int kt = kbase + (it + 1) * 64;
      const int b = (it + 1) & 1;
#pragma unroll
      for (int rr = 0; rr < 2; ++rr) {
        int p = rr * 256 + tid;
        int row = p >> 3;
        int g = (p & 7) ^ (row & 7);
        gld16(kgh + (size_t)(kt + row) * 64 + g * 8, &Ks[b][(p - lane) * 8]);
        gld16(vth + (size_t)row * 4096 + kt + g * 8, &Vs[b][(p - lane) * 8]);
      }
    }
    const u16* ks = Ks[it & 1];
    const u16* vs = Vs[it & 1];

#pragma unroll
    for (int kst = 0; kst < 2; ++kst) {       // 32-k subtile
      const int krow = kst * 32 + q32;
      short8 kf[4];
#pragma unroll
      for (int ds = 0; ds < 4; ++ds) {
        int c = ds * 2 + hf;
        kf[ds] = *(const short8*)&ks[((krow << 3) + (c ^ (krow & 7))) * 8];
      }
      f32x16 s;
#pragma unroll
      for (int r = 0; r < 16; ++r) s[r] = 0.f;
#pragma unroll
      for (int ds = 0; ds < 4; ++ds)
        s = __builtin_amdgcn_mfma_f32_32x32x16_bf16(kf[ds], qf[ds], s, 0, 0, 0);
      unsigned w[8];
      float ls = 0.f;
#pragma unroll
      for (int i = 0; i < 8; ++i) {
        float p0 = __builtin_amdgcn_exp2f(s[2 * i]);
        float p1 = __builtin_amdgcn_exp2f(s[2 * i + 1]);
        ls += p0 + p1;
        asm("v_cvt_pk_bf16_f32 %0, %1, %2" : "=v"(w[i]) : "v"(p0), "v"(p1));
      }
      lrun += ls;
      uint2v r0 = __builtin_amdgcn_permlane32_swap(w[0], w[2], false, false);
      uint2v r1 = __builtin_amdgcn_permlane32_swap(w[1], w[3], false, false);
      uint2v r2 = __builtin_amdgcn_permlane32_swap(w[4], w[6], false, false);
      uint2v r3 = __builtin_amdgcn_permlane32_swap(w[5], w[7], false, false);
      short8 pa[2];
      pa[0] = mk8(r0[0], r1[0], r0[1], r1[1]);   // k-slice kst*32 + [0,16)
      pa[1] = mk8(r2[0], r3[0], r2[1], r3[1]);   // k-slice kst*32 + [16,32)
      // O += P V for this subtile (all in registers; V from swizzled LDS)
#pragma unroll
      for (int dt = 0; dt < 2; ++dt) {
        const int vrow = dt * 32 + q32;
#pragma unroll
        for (int ksl = 0; ksl < 2; ++ksl) {
          int c = kst * 4 + ksl * 2 + hf;
          short8 vf = *(const short8*)&vs[((vrow << 3) + (c ^ (vrow & 7))) * 8];
          oacc[dt] = __builtin_amdgcn_mfma_f32_32x32x16_bf16(pa[ksl], vf, oacc[dt], 0, 0, 0);
        }
      }
    }
  }

  // each half holds a disjoint k-partial of the row sum; combine across halves
  lrun += __shfl_xor(lrun, 32);

  if (kspl > 1) {
    if (hf == 0)
      lpart[((size_t)blockIdx.z * 4096 + qrow + q32) * 12 + h] = lrun;
    float* ob = Opart + (size_t)blockIdx.z * 4096 * 768;
#pragma unroll
    for (int r = 0; r < 16; ++r) {
      int qloc = (r & 3) + 8 * (r >> 2) + 4 * hf;
#pragma unroll
      for (int dt = 0; dt < 2; ++dt)
        ob[(size_t)(qrow + qloc) * 768 + h * 64 + dt * 32 + q32] = oacc[dt][r];
    }
  } else {
    float linv = 1.0f / lrun;
#pragma unroll
    for (int r = 0; r < 16; ++r) {
      int qloc = (r & 3) + 8 * (r >> 2) + 4 * hf;
      float li = __shfl(linv, qloc);
#pragma unroll
      for (int dt = 0; dt < 2; ++dt)
        abo[(size_t)(qrow + qloc) * 768 + h * 64 + dt * 32 + q32] =
            f2bf(oacc[dt][r] * li);
    }
  }
}

// ---------------- merge ksp k-split partials + normalize -> bf16, x4 ----------------
__global__ void merge_norm(const float* __restrict__ Opart, const float* __restrict__ lpart,
                           u16* __restrict__ abo, int ksp) {
  int i = blockIdx.x * 256 + threadIdx.x;   // < 786432 (4096*768/4)
  int s = i / 192, cq = i - s * 192;
  int h = cq >> 4;                          // (cq*4)>>6
  f32x4 a = {0.f, 0.f, 0.f, 0.f};
  float l = 0.f;
  for (int z = 0; z < ksp; ++z) {
    f32x4 b = *(const f32x4*)(Opart + (size_t)z * 4096 * 768 + (size_t)i * 4);
#pragma unroll
    for (int r = 0; r < 4; ++r) a[r] += b[r];
    l += lpart[((size_t)z * 4096 + s) * 12 + h];
  }
  float rl = 1.0f / l;
  u16x4 o;
#pragma unroll
  for (int r = 0; r < 4; ++r) o[r] = f2bf(a[r] * rl);
  *(u16x4*)(abo + (size_t)i * 4) = o;
}

extern "C" void kernel_launch(void* const* d_in, const int* in_sizes, int n_in,
                              void* d_out, int out_size, void* d_ws, size_t ws_size,
                              hipStream_t stream) {
  const float* x   = (const float*)d_in[0];
  const float* wq  = (const float*)d_in[1];
  const float* bq  = (const float*)d_in[2];
  const float* wk  = (const float*)d_in[3];
  const float* bk  = (const float*)d_in[4];
  const float* wv  = (const float*)d_in[5];
  const float* bv  = (const float*)d_in[6];
  const float* wo  = (const float*)d_in[7];
  const float* bo  = (const float*)d_in[8];
  const float* dq  = (const float*)d_in[9];
  const float* uq  = (const float*)d_in[10];
  const float* dk  = (const float*)d_in[11];
  const float* uk  = (const float*)d_in[12];
  const float* dv  = (const float*)d_in[13];
  const float* uv  = (const float*)d_in[14];
  float* out = (float*)d_out;

  char* ws = (char*)d_ws;
  u16* xb    = (u16*)(ws);                 // 4096*768 bf16 (6291456 B); dead after QKV gemm
  u16* ab    = (u16*)(ws);                 // aliases xb: attn output [4096][768] bf16
  u16* weff  = (u16*)(ws + 6291456);       // 2304*768
  u16* wob   = (u16*)(ws + 9830400);       // 768*768
  u16* qb    = (u16*)(ws + 11010048);      // [12][4096][64]
  u16* kb    = (u16*)(ws + 17301504);      // [12][4096][64]
  u16* vtb   = (u16*)(ws + 23592960);      // [12][64][4096]
  float* Op  = (float*)(ws + 29884416);    // [kspl][4096][768] f32 (<= 50331648 B)
  float* lp  = (float*)(ws + 80216064);    // [kspl][4096][12]  f32 (<= 786432 B) -> end 81002496

  int kspl = 1;
  if (ws_size >= 81002496ull) kspl = 4;
  else if (ws_size >= 55443456ull) {
    kspl = 2;
    lp = (float*)(ws + 55050240);          // pack tighter for the 2-split case
  }

  prep_all<<<12288, 256, 0, stream>>>(x, xb, wq, wk, wv, dq, uq, dk, uk, dv, uv, wo, weff, wob);
  gemm_nt<128><<<dim3(32, 18), 256, 0, stream>>>(xb, weff, 768, 0, bq, bk, bv, qb, kb, vtb,
                                                 nullptr, nullptr);
  attn_fwd<<<dim3(32, 12, kspl), 256, 0, stream>>>(qb, kb, vtb, Op, lp, ab, kspl);
  if (kspl > 1) merge_norm<<<3072, 256, 0, stream>>>(Op, lp, ab, kspl);
  gemm_nt<32><<<dim3(128, 6), 256, 0, stream>>>(ab, wob, 768, 1, nullptr, nullptr, nullptr,
                                                nullptr, nullptr, nullptr, bo, out);
}

// Round 5
// 217.368 us; speedup vs baseline: 1.0945x; 1.0011x over previous
//
#include <hip/hip_runtime.h>

typedef unsigned short u16;
typedef __attribute__((ext_vector_type(8))) short short8;    // 8 bf16 (4 VGPRs)
typedef __attribute__((ext_vector_type(4))) float f32x4;
typedef __attribute__((ext_vector_type(16))) float f32x16;
typedef __attribute__((ext_vector_type(4))) unsigned short u16x4;
typedef __attribute__((ext_vector_type(2))) unsigned int uint2v;

typedef __attribute__((address_space(1))) void as1_void;
typedef __attribute__((address_space(3))) void as3_void;

// async global->LDS, 16B per lane; LDS dest = wave-uniform base + lane*16
__device__ __forceinline__ void gld16(const u16* g, u16* l) {
  __builtin_amdgcn_global_load_lds((as1_void*)g, (as3_void*)l, 16, 0, 0);
}

__device__ __forceinline__ u16 f2bf(float f) {
  unsigned u = __float_as_uint(f);
  u += 0x7fffu + ((u >> 16) & 1u);   // RNE
  return (u16)(u >> 16);
}

__device__ __forceinline__ short8 mk8(unsigned a, unsigned b, unsigned c, unsigned d) {
  union { unsigned u[4]; short8 s; } x;
  x.u[0] = a; x.u[1] = b; x.u[2] = c; x.u[3] = d;
  return x.s;
}

// ---------------- fused prep: cvt x (x4) + W_eff + cvt wo ----------------
// blocks [0,3072): x cvt vectorized; [3072,12288): weff rows 0..2303, wob rows 2304..3071
__global__ void prep_all(const float* __restrict__ x, u16* __restrict__ xb,
                         const float* __restrict__ wq, const float* __restrict__ wk, const float* __restrict__ wv,
                         const float* __restrict__ dq, const float* __restrict__ uq,
                         const float* __restrict__ dk, const float* __restrict__ uk,
                         const float* __restrict__ dv, const float* __restrict__ uv,
                         const float* __restrict__ wo, u16* __restrict__ weff, u16* __restrict__ wob) {
  int bid = blockIdx.x;
  if (bid < 3072) {
    int i = bid * 256 + threadIdx.x;          // < 786432
    f32x4 f = *(const f32x4*)(x + (size_t)i * 4);
    u16x4 o;
#pragma unroll
    for (int r = 0; r < 4; ++r) o[r] = f2bf(f[r]);
    *(u16x4*)(xb + (size_t)i * 4) = o;
    return;
  }
  int idx = (bid - 3072) * 256 + threadIdx.x; // < 3072*768
  int n = idx / 768, d = idx - n * 768;
  if (n >= 2304) {
    wob[(n - 2304) * 768 + d] = f2bf(wo[(n - 2304) * 768 + d]);
    return;
  }
  const float *w, *dn, *up; int e;
  if (n < 768)       { w = wq; dn = dq; up = uq; e = n; }
  else if (n < 1536) { w = wk; dn = dk; up = uk; e = n - 768; }
  else               { w = wv; dn = dv; up = uv; e = n - 1536; }
  float acc = w[e * 768 + d];
  float lo = 0.f;
#pragma unroll
  for (int r = 0; r < 8; ++r) lo += up[e * 8 + r] * dn[r * 768 + d];
  weff[idx] = f2bf(acc + 2.0f * lo);   // SCALING = alpha/rank = 2
}

// ---------------- NT GEMM: C[m,n] = sum_k A[m,k]*B[n,k] (+bias) ----------------
// MT x 128 block tile, BK=32, 256 thr. MT=128: 2x2 waves of 64x64. MT=32: 1x4 waves of 32x32.
// mode 0: N=2304 -> q[h][s][64] (pre-scaled by 0.125*log2e), k[h][s][64], vt[h][64][s]
// mode 1: N=768  -> fo[s][768] fp32 (+bo)
template <int MT>
__global__ __launch_bounds__(256) void gemm_nt(
    const u16* __restrict__ A, const u16* __restrict__ B, int K, int mode,
    const float* __restrict__ bq, const float* __restrict__ bk, const float* __restrict__ bv,
    u16* __restrict__ qo, u16* __restrict__ ko, u16* __restrict__ vto,
    const float* __restrict__ bo, float* __restrict__ fo) {
  constexpr int TI = (MT == 128) ? 4 : 2;
  constexpr int TJ = (MT == 128) ? 4 : 2;
  __shared__ u16 As[MT * 32];
  __shared__ u16 Bs[128 * 32];
  const int tid = threadIdx.x;
  const int lane = tid & 63;
  const int wid = tid >> 6;
  const int qd = lane >> 4;
  const int m16 = lane & 15;
  const int rowbase = (MT == 128) ? (wid >> 1) * 64 : 0;
  const int colbase = (MT == 128) ? (wid & 1) * 64 : wid * 32;
  const int m0 = blockIdx.x * MT, n0 = blockIdx.y * 128;

  f32x4 acc[TI][TJ];
#pragma unroll
  for (int i = 0; i < TI; ++i)
#pragma unroll
    for (int j = 0; j < TJ; ++j)
#pragma unroll
      for (int e = 0; e < 4; ++e) acc[i][j][e] = 0.f;

  for (int k0 = 0; k0 < K; k0 += 32) {
    __syncthreads();
#pragma unroll
    for (int p = tid; p < MT * 4; p += 256) {
      int row = p >> 2;
      int g = (p & 3) ^ ((row >> 1) & 3);
      gld16(A + (size_t)(m0 + row) * K + k0 + g * 8, &As[(p - lane) * 8]);
    }
#pragma unroll
    for (int p = tid; p < 512; p += 256) {
      int row = p >> 2;
      int g = (p & 3) ^ ((row >> 1) & 3);
      gld16(B + (size_t)(n0 + row) * K + k0 + g * 8, &Bs[(p - lane) * 8]);
    }
    __syncthreads();
    short8 af[TI], bf[TJ];
#pragma unroll
    for (int i = 0; i < TI; ++i) {
      int ar = rowbase + i * 16 + m16;
      af[i] = *(const short8*)&As[(ar * 4 + (qd ^ ((ar >> 1) & 3))) * 8];
    }
#pragma unroll
    for (int j = 0; j < TJ; ++j) {
      int br = colbase + j * 16 + m16;
      bf[j] = *(const short8*)&Bs[(br * 4 + (qd ^ ((br >> 1) & 3))) * 8];
    }
#pragma unroll
    for (int i = 0; i < TI; ++i)
#pragma unroll
      for (int j = 0; j < TJ; ++j)
        acc[i][j] = __builtin_amdgcn_mfma_f32_16x16x32_bf16(af[i], bf[j], acc[i][j], 0, 0, 0);
  }

  // C/D layout: col = m16, row = qd*4 + reg
#pragma unroll
  for (int i = 0; i < TI; ++i) {
    int gr = m0 + rowbase + i * 16 + qd * 4;
#pragma unroll
    for (int j = 0; j < TJ; ++j) {
      int gc = n0 + colbase + j * 16 + m16;
      if (mode == 0) {
        if (gc < 768) {
          float bias = bq[gc];
          int h = gc >> 6, d = gc & 63;
          // fold attention scale 1/8 and log2(e) into Q: exp(x/8) = exp2(x*0.18034)
#pragma unroll
          for (int r = 0; r < 4; ++r)
            qo[((size_t)h * 4096 + gr + r) * 64 + d] = f2bf((acc[i][j][r] + bias) * 0.18033688f);
        } else if (gc < 1536) {
          int c = gc - 768;
          float bias = bk[c];
          int h = c >> 6, d = c & 63;
#pragma unroll
          for (int r = 0; r < 4; ++r)
            ko[((size_t)h * 4096 + gr + r) * 64 + d] = f2bf(acc[i][j][r] + bias);
        } else {
          int c = gc - 1536;
          float bias = bv[c];
          int h = c >> 6, d = c & 63;
          u16x4 pk;
#pragma unroll
          for (int r = 0; r < 4; ++r) pk[r] = f2bf(acc[i][j][r] + bias);
          *(u16x4*)&vto[((size_t)h * 64 + d) * 4096 + gr] = pk;
        }
      } else {
        float bias = bo[gc];
#pragma unroll
        for (int r = 0; r < 4; ++r)
          fo[(size_t)(gr + r) * 768 + gc] = acc[i][j][r] + bias;
      }
    }
  }
}

// ---------------- flash attention fwd (S^T form, fixed-max base-2 softmax) ----------------
// grid (12*kspl groups=(h,z), 32 qblocks), 256 thr / 4 waves. Wave owns ONE 32-q-row tile.
// ROUND-2 PROVEN SYNC STRUCTURE (syncthreads double-buffer) — rounds 3/4's raw-s_barrier +
// counted-vmcnt pipeline killed the container twice; reverted. Changes vs round 2 are
// indexing-only + setprio:
//  * XCD clustering (T1): linear id = grp + 24*qb, 24%8==0 -> id%8 = grp%8, so all 32
//    q-blocks sharing one (h,z) K/V stream land on one XCD; 3 streams/XCD x 512KB = 1.5MB,
//    L2-resident -> K/V refetch becomes L2 hits.
//  * kspl=2: 768 blocks = exactly 3/CU at 32KB LDS (full residency, no dispatch tail),
//    halves Opart/merge traffic vs kspl=4.
//  * T5 setprio(1) around MFMA clusters.
// 32x32x16 MFMA. Swapped QK^T: S^T = K*Q^T, lane (q32=lane&31, hf=lane>>5) holds 16 scores
// of q-row q32, k = (reg&3)+8*(reg>>2)+4*hf. Softmax in-register; P for PV built via
// v_cvt_pk_bf16_f32 + permlane32_swap pairing (w0,w2)/(w1,w3) -> A-frag layout k=(l>>5)*8+j.
// K buf 64x64 (8 chunks/row, phys = row*8 + (c ^ (row&7))); V^T buf 64d x 64k same swizzle,
// DOUBLE-BUFFERED with ONE barrier per iter (issue gld16 for it+1 right after barrier).
// LDS = 2*8K (Ks) + 2*8K (Vs) = 32 KB.
__global__ __launch_bounds__(256) void attn_fwd(
    const u16* __restrict__ Q, const u16* __restrict__ Kg, const u16* __restrict__ Vt,
    float* __restrict__ Opart, float* __restrict__ lpart, u16* __restrict__ abo, int kspl) {
  __shared__ u16 Ks[2][64 * 64];
  __shared__ u16 Vs[2][64 * 64];
  const int tid = threadIdx.x, lane = tid & 63, wid = tid >> 6;
  const int q32 = lane & 31, hf = lane >> 5;
  const int grp = blockIdx.x;
  const int h = grp / kspl;
  const int z = grp - h * kspl;
  const int qrow = blockIdx.y * 128 + wid * 32;
  const int kbase = z * (4096 / kspl);
  const int niter = (4096 / kspl) >> 6;

  const u16* kgh = Kg + (size_t)h * 4096 * 64;
  const u16* vth = Vt + (size_t)h * 64 * 4096;

  // Q fragment (B-operand of K*Q^T): qf[ds] = Q[qrow+q32][ds*16 + hf*8 ..+8)
  short8 qf[4];
  {
    const u16* qb = Q + ((size_t)h * 4096 + qrow + q32) * 64 + hf * 8;
#pragma unroll
    for (int ds = 0; ds < 4; ++ds) qf[ds] = *(const short8*)(qb + ds * 16);
  }

  float lrun = 0.f;
  f32x16 oacc[2];
#pragma unroll
  for (int d = 0; d < 2; ++d)
#pragma unroll
    for (int r = 0; r < 16; ++r) oacc[d][r] = 0.f;

  // prologue: stage iter 0 into buffer 0
  {
    const int kt = kbase;
#pragma unroll
    for (int rr = 0; rr < 2; ++rr) {
      int p = rr * 256 + tid;                 // 0..511 chunks
      int row = p >> 3;
      int g = (p & 7) ^ (row & 7);
      gld16(kgh + (size_t)(kt + row) * 64 + g * 8, &Ks[0][(p - lane) * 8]);
      gld16(vth + (size_t)row * 4096 + kt + g * 8, &Vs[0][(p - lane) * 8]);
    }
  }

  for (int it = 0; it < niter; ++it) {
    __syncthreads();   // buf[it&1] staged (issued last iter); prev reads of buf^1 done
    if (it + 1 < niter) {
      const int kt = kbase + (it + 1) * 64;
      const int b = (it + 1) & 1;
#pragma unroll
      for (int rr = 0; rr < 2; ++rr) {
        int p = rr * 256 + tid;
        int row = p >> 3;
        int g = (p & 7) ^ (row & 7);
        gld16(kgh + (size_t)(kt + row) * 64 + g * 8, &Ks[b][(p - lane) * 8]);
        gld16(vth + (size_t)row * 4096 + kt + g * 8, &Vs[b][(p - lane) * 8]);
      }
    }
    const u16* ks = Ks[it & 1];
    const u16* vs = Vs[it & 1];

#pragma unroll
    for (int kst = 0; kst < 2; ++kst) {       // 32-k subtile
      const int krow = kst * 32 + q32;
      short8 kf[4];
#pragma unroll
      for (int ds = 0; ds < 4; ++ds) {
        int c = ds * 2 + hf;
        kf[ds] = *(const short8*)&ks[((krow << 3) + (c ^ (krow & 7))) * 8];
      }
      f32x16 s;
#pragma unroll
      for (int r = 0; r < 16; ++r) s[r] = 0.f;
      __builtin_amdgcn_s_setprio(1);
#pragma unroll
      for (int ds = 0; ds < 4; ++ds)
        s = __builtin_amdgcn_mfma_f32_32x32x16_bf16(kf[ds], qf[ds], s, 0, 0, 0);
      __builtin_amdgcn_s_setprio(0);
      unsigned w[8];
      float ls = 0.f;
#pragma unroll
      for (int i = 0; i < 8; ++i) {
        float p0 = __builtin_amdgcn_exp2f(s[2 * i]);
        float p1 = __builtin_amdgcn_exp2f(s[2 * i + 1]);
        ls += p0 + p1;
        asm("v_cvt_pk_bf16_f32 %0, %1, %2" : "=v"(w[i]) : "v"(p0), "v"(p1));
      }
      lrun += ls;
      uint2v r0 = __builtin_amdgcn_permlane32_swap(w[0], w[2], false, false);
      uint2v r1 = __builtin_amdgcn_permlane32_swap(w[1], w[3], false, false);
      uint2v r2 = __builtin_amdgcn_permlane32_swap(w[4], w[6], false, false);
      uint2v r3 = __builtin_amdgcn_permlane32_swap(w[5], w[7], false, false);
      short8 pa[2];
      pa[0] = mk8(r0[0], r1[0], r0[1], r1[1]);   // k-slice kst*32 + [0,16)
      pa[1] = mk8(r2[0], r3[0], r2[1], r3[1]);   // k-slice kst*32 + [16,32)
      // O += P V for this subtile (all in registers; V from swizzled LDS)
      __builtin_amdgcn_s_setprio(1);
#pragma unroll
      for (int dt = 0; dt < 2; ++dt) {
        const int vrow = dt * 32 + q32;
#pragma unroll
        for (int ksl = 0; ksl < 2; ++ksl) {
          int c = kst * 4 + ksl * 2 + hf;
          short8 vf = *(const short8*)&vs[((vrow << 3) + (c ^ (vrow & 7))) * 8];
          oacc[dt] = __builtin_amdgcn_mfma_f32_32x32x16_bf16(pa[ksl], vf, oacc[dt], 0, 0, 0);
        }
      }
      __builtin_amdgcn_s_setprio(0);
    }
  }

  // each half holds a disjoint k-partial of the row sum; combine across halves
  lrun += __shfl_xor(lrun, 32);

  if (kspl > 1) {
    if (hf == 0)
      lpart[((size_t)z * 4096 + qrow + q32) * 12 + h] = lrun;
    float* ob = Opart + (size_t)z * 4096 * 768;
#pragma unroll
    for (int r = 0; r < 16; ++r) {
      int qloc = (r & 3) + 8 * (r >> 2) + 4 * hf;
#pragma unroll
      for (int dt = 0; dt < 2; ++dt)
        ob[(size_t)(qrow + qloc) * 768 + h * 64 + dt * 32 + q32] = oacc[dt][r];
    }
  } else {
    float linv = 1.0f / lrun;
#pragma unroll
    for (int r = 0; r < 16; ++r) {
      int qloc = (r & 3) + 8 * (r >> 2) + 4 * hf;
      float li = __shfl(linv, qloc);
#pragma unroll
      for (int dt = 0; dt < 2; ++dt)
        abo[(size_t)(qrow + qloc) * 768 + h * 64 + dt * 32 + q32] =
            f2bf(oacc[dt][r] * li);
    }
  }
}

// ---------------- merge ksp k-split partials + normalize -> bf16, x4 ----------------
__global__ void merge_norm(const float* __restrict__ Opart, const float* __restrict__ lpart,
                           u16* __restrict__ abo, int ksp) {
  int i = blockIdx.x * 256 + threadIdx.x;   // < 786432 (4096*768/4)
  int s = i / 192, cq = i - s * 192;
  int h = cq >> 4;                          // (cq*4)>>6
  f32x4 a = {0.f, 0.f, 0.f, 0.f};
  float l = 0.f;
  for (int z = 0; z < ksp; ++z) {
    f32x4 b = *(const f32x4*)(Opart + (size_t)z * 4096 * 768 + (size_t)i * 4);
#pragma unroll
    for (int r = 0; r < 4; ++r) a[r] += b[r];
    l += lpart[((size_t)z * 4096 + s) * 12 + h];
  }
  float rl = 1.0f / l;
  u16x4 o;
#pragma unroll
  for (int r = 0; r < 4; ++r) o[r] = f2bf(a[r] * rl);
  *(u16x4*)(abo + (size_t)i * 4) = o;
}

extern "C" void kernel_launch(void* const* d_in, const int* in_sizes, int n_in,
                              void* d_out, int out_size, void* d_ws, size_t ws_size,
                              hipStream_t stream) {
  const float* x   = (const float*)d_in[0];
  const float* wq  = (const float*)d_in[1];
  const float* bq  = (const float*)d_in[2];
  const float* wk  = (const float*)d_in[3];
  const float* bk  = (const float*)d_in[4];
  const float* wv  = (const float*)d_in[5];
  const float* bv  = (const float*)d_in[6];
  const float* wo  = (const float*)d_in[7];
  const float* bo  = (const float*)d_in[8];
  const float* dq  = (const float*)d_in[9];
  const float* uq  = (const float*)d_in[10];
  const float* dk  = (const float*)d_in[11];
  const float* uk  = (const float*)d_in[12];
  const float* dv  = (const float*)d_in[13];
  const float* uv  = (const float*)d_in[14];
  float* out = (float*)d_out;

  char* ws = (char*)d_ws;
  u16* xb    = (u16*)(ws);                 // 4096*768 bf16 (6291456 B); dead after QKV gemm
  u16* ab    = (u16*)(ws);                 // aliases xb: attn output [4096][768] bf16
  u16* weff  = (u16*)(ws + 6291456);       // 2304*768
  u16* wob   = (u16*)(ws + 9830400);       // 768*768
  u16* qb    = (u16*)(ws + 11010048);      // [12][4096][64]
  u16* kb    = (u16*)(ws + 17301504);      // [12][4096][64]
  u16* vtb   = (u16*)(ws + 23592960);      // [12][64][4096]
  float* Op  = (float*)(ws + 29884416);    // [kspl][4096][768] f32 (kspl=2 -> 25165824 B)
  float* lp  = (float*)(ws + 55050240);    // [kspl][4096][12]  f32 -> end 55443456

  // kspl=2 -> grid 768 blocks = exactly 3/CU at 32 KB LDS (full residency, minimal merge)
  int kspl = 1;
  if (ws_size >= 55443456ull) kspl = 2;

  prep_all<<<12288, 256, 0, stream>>>(x, xb, wq, wk, wv, dq, uq, dk, uk, dv, uv, wo, weff, wob);
  gemm_nt<128><<<dim3(32, 18), 256, 0, stream>>>(xb, weff, 768, 0, bq, bk, bv, qb, kb, vtb,
                                                 nullptr, nullptr);
  attn_fwd<<<dim3(12 * kspl, 32), 256, 0, stream>>>(qb, kb, vtb, Op, lp, ab, kspl);
  if (kspl > 1) merge_norm<<<3072, 256, 0, stream>>>(Op, lp, ab, kspl);
  gemm_nt<32><<<dim3(128, 6), 256, 0, stream>>>(ab, wob, 768, 1, nullptr, nullptr, nullptr,
                                                nullptr, nullptr, nullptr, bo, out);
}